// Round 2
// baseline (3143.940 us; speedup 1.0000x reference)
//
#include <hip/hip_runtime.h>
#include <hip/hip_bf16.h>

#define N_NODES 50000
#define N_EDGES 800000
#define N_REL 8
#define HID 256
#define N_BASES 30
#define TOTB (N_REL * N_NODES)                 // 400000 buckets (r, dst)
#define SCAN_NBLK ((TOTB + 1023) / 1024)       // 391

typedef float f4v __attribute__((ext_vector_type(4)));
typedef short sh8 __attribute__((ext_vector_type(8)));

static __device__ __forceinline__ short f2bf(float f) {
  return __builtin_bit_cast(short, __float2bfloat16(f));
}

// ---------------- preprocessing ----------------

__global__ void k_count(const int* __restrict__ eidx, const int* __restrict__ etyp,
                        unsigned* __restrict__ counts) {
  int e = blockIdx.x * 256 + threadIdx.x;
  if (e < N_EDGES) {
    int dst = eidx[N_EDGES + e];
    int et  = etyp[e];
    atomicAdd(&counts[et * N_NODES + dst], 1u);
  }
}

__global__ void k_deginv(const unsigned* __restrict__ counts, float* __restrict__ deginv) {
  int d = blockIdx.x * 256 + threadIdx.x;
  if (d < N_NODES) {
    unsigned deg = 0;
#pragma unroll
    for (int r = 0; r < N_REL; r++) deg += counts[r * N_NODES + d];
    deginv[d] = 1.0f / (float)(deg ? deg : 1u);
  }
}

__global__ void k_scanA(const unsigned* __restrict__ counts, unsigned* __restrict__ partials) {
  __shared__ unsigned sm[256];
  int t = threadIdx.x, b = blockIdx.x;
  int g0 = b * 1024 + t * 4;
  unsigned s = 0;
#pragma unroll
  for (int j = 0; j < 4; j++) s += (g0 + j < TOTB) ? counts[g0 + j] : 0u;
  sm[t] = s;
  __syncthreads();
  for (int st = 128; st > 0; st >>= 1) {
    if (t < st) sm[t] += sm[t + st];
    __syncthreads();
  }
  if (t == 0) partials[b] = sm[0];
}

__global__ void k_scanB(unsigned* __restrict__ partials) {
  __shared__ unsigned sm[512];
  int t = threadIdx.x;
  unsigned v = (t < SCAN_NBLK) ? partials[t] : 0u;
  sm[t] = v;
  __syncthreads();
  for (int s = 1; s < 512; s <<= 1) {
    unsigned add = (t >= s) ? sm[t - s] : 0u;
    __syncthreads();
    sm[t] += add;
    __syncthreads();
  }
  partials[t] = sm[t] - v;  // exclusive
}

__global__ void k_scanC(const unsigned* __restrict__ counts, const unsigned* __restrict__ partials,
                        unsigned* __restrict__ offsets) {
  __shared__ unsigned sm[256];
  int t = threadIdx.x, b = blockIdx.x;
  int g0 = b * 1024 + t * 4;
  unsigned c[4];
#pragma unroll
  for (int j = 0; j < 4; j++) c[j] = (g0 + j < TOTB) ? counts[g0 + j] : 0u;
  unsigned tsum = c[0] + c[1] + c[2] + c[3];
  sm[t] = tsum;
  __syncthreads();
  for (int s = 1; s < 256; s <<= 1) {
    unsigned add = (t >= s) ? sm[t - s] : 0u;
    __syncthreads();
    sm[t] += add;
    __syncthreads();
  }
  unsigned run = partials[b] + (sm[t] - tsum);
#pragma unroll
  for (int j = 0; j < 4; j++) {
    if (g0 + j < TOTB) offsets[g0 + j] = run;
    if (g0 + j == TOTB - 1) offsets[TOTB] = run + c[j];
    run += c[j];
  }
}

// cursors buffer == counts buffer (re-zeroed after scans consumed counts)
__global__ void k_place(const int* __restrict__ eidx, const int* __restrict__ etyp,
                        const unsigned* __restrict__ offsets, unsigned* __restrict__ cursors,
                        unsigned* __restrict__ payload) {
  int e = blockIdx.x * 256 + threadIdx.x;
  if (e < N_EDGES) {
    int src = eidx[e];
    int dst = eidx[N_EDGES + e];
    int et  = etyp[e];
    int b = et * N_NODES + dst;
    unsigned pos = offsets[b] + atomicAdd(&cursors[b], 1u);
    payload[pos] = ((unsigned)dst << 16) | (unsigned)src;  // both < 65536
  }
}

// W[l][r] = sum_b coeffs[l][r][b] * bases[l][b]  (r=8 -> self_loops[l])
// stored transposed as Wb[l][r][o][k] bf16 so MFMA B-fragments are contiguous.
__global__ void k_wbuild(const float* __restrict__ bases, const float* __restrict__ coeffs,
                         const float* __restrict__ selfl, short* __restrict__ Wb) {
  int bid = blockIdx.x;
  int k = bid & 255;
  int lr = bid >> 8;  // 0..17
  int r = lr % 9, l = lr / 9;
  int o = threadIdx.x;
  float v;
  if (r == 8) {
    v = selfl[((size_t)l * HID + k) * HID + o];
  } else {
    const float* cf = coeffs + (l * N_REL + r) * N_BASES;
    const float* bp = bases + (((size_t)l * N_BASES) * HID + k) * HID + o;
    float a = 0.f;
#pragma unroll
    for (int b = 0; b < N_BASES; b++) a += cf[b] * bp[(size_t)b * HID * HID];
    v = a;
  }
  Wb[(((size_t)l * 9 + r) * HID + o) * HID + k] = f2bf(v);
}

// ---------------- fused layer kernel ----------------
// Block: 64 dst nodes, 256 threads (4 waves; wave w owns output cols [64w,64w+64)).
// Per relation r: build S[64][256] (f32, XOR-swizzled 16B chunks) in LDS from the
// sorted edge list, then MFMA-accumulate S @ W[r]. r=8 is the self-loop (S = x rows).

__global__ __launch_bounds__(256, 2) void k_layer(
    const float* __restrict__ x, float* __restrict__ out,
    const short* __restrict__ Wb, const unsigned* __restrict__ offsets,
    const unsigned* __restrict__ payload, const float* __restrict__ deginv,
    const int relu) {
  __shared__ __attribute__((aligned(16))) float S[64 * 256];
  f4v* S4 = (f4v*)S;
  const int tid  = threadIdx.x;
  const int lane = tid & 63;
  const int wv   = tid >> 6;
  const int lhi  = lane >> 4;
  const int llo  = lane & 15;
  const int t0   = blockIdx.x * 64;
  const int tend = (t0 + 64 < N_NODES) ? (t0 + 64) : N_NODES;

  f4v acc[4][4];
#pragma unroll
  for (int m = 0; m < 4; m++)
#pragma unroll
    for (int n = 0; n < 4; n++) acc[m][n] = (f4v){0.f, 0.f, 0.f, 0.f};

  for (int r = 0; r < 9; ++r) {
    if (r < 8) {
      // zero S
#pragma unroll
      for (int i = tid; i < 4096; i += 256) S4[i] = (f4v){0.f, 0.f, 0.f, 0.f};
      __syncthreads();
      const unsigned start = offsets[r * N_NODES + t0];
      const unsigned end   = offsets[r * N_NODES + tend];
      // gather: 4 edges per wave-iteration for ILP; each lane carries 16B of a row
      for (unsigned p0 = start + (unsigned)(wv << 2); p0 < end; p0 += 16) {
        unsigned pl[4];
        float dv[4];
        int row[4];
        f4v xv[4];
#pragma unroll
        for (int u = 0; u < 4; u++) {
          unsigned p = p0 + u;
          pl[u] = payload[(p < end) ? p : p0];
        }
#pragma unroll
        for (int u = 0; u < 4; u++) {
          int src = pl[u] & 0xFFFF;
          int dst = (int)(pl[u] >> 16);
          row[u] = dst - t0;
          dv[u] = (p0 + u < end) ? deginv[dst] : 0.f;  // tail adds 0
          xv[u] = *(const f4v*)(x + (size_t)src * HID + (lane << 2));
        }
#pragma unroll
        for (int u = 0; u < 4; u++) {
          float* sp = S + row[u] * HID + ((lane ^ (row[u] & 7)) << 2);
          atomicAdd(sp + 0, xv[u].x * dv[u]);
          atomicAdd(sp + 1, xv[u].y * dv[u]);
          atomicAdd(sp + 2, xv[u].z * dv[u]);
          atomicAdd(sp + 3, xv[u].w * dv[u]);
        }
      }
    } else {
      // self-loop: S = x rows (no deg_inv)
#pragma unroll
      for (int i = tid; i < 4096; i += 256) {
        int rw = i >> 6, c4 = i & 63;
        int g = t0 + rw;
        f4v v = (f4v){0.f, 0.f, 0.f, 0.f};
        if (g < N_NODES) v = *(const f4v*)(x + (size_t)g * HID + (c4 << 2));
        S4[(rw << 6) + (c4 ^ (rw & 7))] = v;
      }
    }
    __syncthreads();
    // MFMA: acc += S(64x256) @ W[r](256x256), wave wv does cols [64wv, 64wv+64)
    const short* wb = Wb + (size_t)r * HID * HID;
#pragma unroll
    for (int kk = 0; kk < 8; ++kk) {
      sh8 af[4], bfr[4];
#pragma unroll
      for (int m = 0; m < 4; m++) {
        int rw = m * 16 + llo;
        int c0 = kk * 8 + lhi * 2;
        int s = llo & 7;
        f4v p = S4[(rw << 6) + (c0 ^ s)];
        f4v q = S4[(rw << 6) + ((c0 + 1) ^ s)];
        sh8 t;
        t[0] = f2bf(p.x); t[1] = f2bf(p.y); t[2] = f2bf(p.z); t[3] = f2bf(p.w);
        t[4] = f2bf(q.x); t[5] = f2bf(q.y); t[6] = f2bf(q.z); t[7] = f2bf(q.w);
        af[m] = t;
      }
#pragma unroll
      for (int n = 0; n < 4; n++) {
        int col = (wv << 6) + n * 16 + llo;
        bfr[n] = *(const sh8*)(wb + (size_t)col * HID + kk * 32 + lhi * 8);
      }
#pragma unroll
      for (int m = 0; m < 4; m++)
#pragma unroll
        for (int n = 0; n < 4; n++)
          acc[m][n] = __builtin_amdgcn_mfma_f32_16x16x32_bf16(af[m], bfr[n], acc[m][n], 0, 0, 0);
    }
    __syncthreads();
  }
  // epilogue: D frag mapping col=lane&15, row=4*(lane>>4)+j
#pragma unroll
  for (int m = 0; m < 4; m++) {
#pragma unroll
    for (int n = 0; n < 4; n++) {
      int col = (wv << 6) + n * 16 + llo;
#pragma unroll
      for (int j = 0; j < 4; j++) {
        int rw = t0 + m * 16 + lhi * 4 + j;
        if (rw < N_NODES) {
          float v = acc[m][n][j];
          if (relu) v = fmaxf(v, 0.f);
          out[(size_t)rw * HID + col] = v;
        }
      }
    }
  }
}

// ---------------- launch ----------------

extern "C" void kernel_launch(void* const* d_in, const int* in_sizes, int n_in,
                              void* d_out, int out_size, void* d_ws, size_t ws_size,
                              hipStream_t stream) {
  const int*   eidx   = (const int*)d_in[0];
  const int*   etyp   = (const int*)d_in[1];
  const float* emb    = (const float*)d_in[3];
  const float* bases  = (const float*)d_in[4];
  const float* coeffs = (const float*)d_in[5];
  const float* selfl  = (const float*)d_in[6];
  float* outp = (float*)d_out;

  char* w = (char*)d_ws;
  size_t off = 0;
  auto alloc = [&](size_t bytes) -> void* {
    void* p = w + off;
    off = (off + bytes + 255) & ~(size_t)255;
    return p;
  };
  unsigned* counts   = (unsigned*)alloc((size_t)TOTB * 4);        // doubles as cursors
  unsigned* offsets  = (unsigned*)alloc((size_t)(TOTB + 1) * 4);
  unsigned* partials = (unsigned*)alloc(512 * 4);
  float*    deginv   = (float*)alloc((size_t)N_NODES * 4);
  unsigned* payload  = (unsigned*)alloc((size_t)N_EDGES * 4);
  short*    Wb       = (short*)alloc((size_t)2 * 9 * HID * HID * 2);
  float*    x1       = (float*)alloc((size_t)N_NODES * HID * 4);
  (void)ws_size; (void)in_sizes; (void)n_in; (void)out_size;

  hipMemsetAsync(counts, 0, (size_t)TOTB * 4, stream);

  k_count<<<(N_EDGES + 255) / 256, 256, 0, stream>>>(eidx, etyp, counts);
  k_deginv<<<(N_NODES + 255) / 256, 256, 0, stream>>>(counts, deginv);
  k_scanA<<<SCAN_NBLK, 256, 0, stream>>>(counts, partials);
  k_scanB<<<1, 512, 0, stream>>>(partials);
  k_scanC<<<SCAN_NBLK, 256, 0, stream>>>(counts, partials, offsets);
  hipMemsetAsync(counts, 0, (size_t)TOTB * 4, stream);  // reuse as cursors
  k_place<<<(N_EDGES + 255) / 256, 256, 0, stream>>>(eidx, etyp, offsets, counts, payload);
  k_wbuild<<<2 * 9 * HID, 256, 0, stream>>>(bases, coeffs, selfl, Wb);

  const int nblk = (N_NODES + 63) / 64;
  k_layer<<<nblk, 256, 0, stream>>>(emb, x1, Wb, offsets, payload, deginv, 1);
  k_layer<<<nblk, 256, 0, stream>>>(x1, outp, Wb + (size_t)9 * HID * HID, offsets, payload, deginv, 0);
}

// Round 6
// 641.806 us; speedup vs baseline: 4.8986x; 4.8986x over previous
//
#include <hip/hip_runtime.h>
#include <hip/hip_bf16.h>

#define N_NODES 50000
#define NP 50048                      // padded rows = 391*128
#define N_EDGES 800000
#define N_REL 8
#define HID 256
#define N_BASES 30
#define SCAN_NBLK ((N_NODES + 1023) / 1024)   // 49

typedef float f4v __attribute__((ext_vector_type(4)));
typedef short sh8 __attribute__((ext_vector_type(8)));

static __device__ __forceinline__ short f2bf(float f) {
  return __builtin_bit_cast(short, __float2bfloat16(f));
}
static __device__ __forceinline__ float bf2f(unsigned short u) {
  return __builtin_bit_cast(float, ((unsigned)u) << 16);
}

// ---------------- preprocessing ----------------

__global__ void k_count(const int* __restrict__ eidx, unsigned* __restrict__ counts) {
  int e = blockIdx.x * 256 + threadIdx.x;
  if (e < N_EDGES) atomicAdd(&counts[eidx[N_EDGES + e]], 1u);
}

__global__ void k_deginv(const unsigned* __restrict__ counts, float* __restrict__ deginv) {
  int d = blockIdx.x * 256 + threadIdx.x;
  if (d < N_NODES) {
    unsigned deg = counts[d];
    deginv[d] = 1.0f / (float)(deg ? deg : 1u);
  }
}

__global__ void k_scanA(const unsigned* __restrict__ counts, unsigned* __restrict__ partials) {
  __shared__ unsigned sm[256];
  int t = threadIdx.x, b = blockIdx.x;
  int g0 = b * 1024 + t * 4;
  unsigned s = 0;
#pragma unroll
  for (int j = 0; j < 4; j++) s += (g0 + j < N_NODES) ? counts[g0 + j] : 0u;
  sm[t] = s;
  __syncthreads();
  for (int st = 128; st > 0; st >>= 1) {
    if (t < st) sm[t] += sm[t + st];
    __syncthreads();
  }
  if (t == 0) partials[b] = sm[0];
}

__global__ void k_scanB(unsigned* __restrict__ partials) {
  __shared__ unsigned sm[512];
  int t = threadIdx.x;
  unsigned v = (t < SCAN_NBLK) ? partials[t] : 0u;
  sm[t] = v;
  __syncthreads();
  for (int s = 1; s < 512; s <<= 1) {
    unsigned add = (t >= s) ? sm[t - s] : 0u;
    __syncthreads();
    sm[t] += add;
    __syncthreads();
  }
  partials[t] = sm[t] - v;  // exclusive
}

__global__ void k_scanC(const unsigned* __restrict__ counts, const unsigned* __restrict__ partials,
                        unsigned* __restrict__ offsets) {
  __shared__ unsigned sm[256];
  int t = threadIdx.x, b = blockIdx.x;
  int g0 = b * 1024 + t * 4;
  unsigned c[4];
#pragma unroll
  for (int j = 0; j < 4; j++) c[j] = (g0 + j < N_NODES) ? counts[g0 + j] : 0u;
  unsigned tsum = c[0] + c[1] + c[2] + c[3];
  sm[t] = tsum;
  __syncthreads();
  for (int s = 1; s < 256; s <<= 1) {
    unsigned add = (t >= s) ? sm[t - s] : 0u;
    __syncthreads();
    sm[t] += add;
    __syncthreads();
  }
  unsigned run = partials[b] + (sm[t] - tsum);
#pragma unroll
  for (int j = 0; j < 4; j++) {
    if (g0 + j < N_NODES) offsets[g0 + j] = run;
    if (g0 + j == N_NODES - 1) offsets[N_NODES] = run + c[j];
    run += c[j];
  }
}

// cursors buffer == counts buffer (re-zeroed after scans consumed counts)
__global__ void k_place(const int* __restrict__ eidx, const int* __restrict__ etyp,
                        const unsigned* __restrict__ offsets, unsigned* __restrict__ cursors,
                        unsigned* __restrict__ payload) {
  int e = blockIdx.x * 256 + threadIdx.x;
  if (e < N_EDGES) {
    int src = eidx[e];
    int dst = eidx[N_EDGES + e];
    int et  = etyp[e];
    unsigned pos = offsets[dst] + atomicAdd(&cursors[dst], 1u);
    payload[pos] = ((unsigned)et << 16) | (unsigned)src;  // et<8, src<65536
  }
}

// W[l][r] = sum_b coeffs[l][r][b]*bases[l][b]; r=8 -> self_loops[l].
// Stored as Wb[l][r][o][k] bf16 (k contiguous) = MFMA B-fragment layout.
__global__ void k_wbuild(const float* __restrict__ bases, const float* __restrict__ coeffs,
                         const float* __restrict__ selfl, short* __restrict__ Wb) {
  int bid = blockIdx.x;
  int k = bid & 255;
  int lr = bid >> 8;  // 0..17
  int r = lr % 9, l = lr / 9;
  int o = threadIdx.x;
  float v;
  if (r == 8) {
    v = selfl[((size_t)l * HID + k) * HID + o];
  } else {
    const float* cf = coeffs + (l * N_REL + r) * N_BASES;
    const float* bp = bases + (((size_t)l * N_BASES) * HID + k) * HID + o;
    float a = 0.f;
#pragma unroll
    for (int b = 0; b < N_BASES; b++) a += cf[b] * bp[(size_t)b * HID * HID];
    v = a;
  }
  Wb[(((size_t)l * 9 + r) * HID + o) * HID + k] = f2bf(v);
}

// f32 -> bf16 convert with zero-padding rows [N_NODES, NP)
__global__ void k_tobf16(const float* __restrict__ src, short* __restrict__ dstp) {
  int i = blockIdx.x * 256 + threadIdx.x;   // index of 8-float group
  if (i >= NP * (HID / 8)) return;
  int row = i >> 5;                          // 32 groups per row
  sh8 v;
  if (row < N_NODES) {
    const float* s = src + (size_t)i * 8;
    f4v a = *(const f4v*)s, b = *(const f4v*)(s + 4);
    v[0] = f2bf(a.x); v[1] = f2bf(a.y); v[2] = f2bf(a.z); v[3] = f2bf(a.w);
    v[4] = f2bf(b.x); v[5] = f2bf(b.y); v[6] = f2bf(b.z); v[7] = f2bf(b.w);
  } else {
    v = (sh8){0, 0, 0, 0, 0, 0, 0, 0};
  }
  *(sh8*)(dstp + (size_t)i * 8) = v;
}

// ---------------- GEMM: H[NP][ncols] = A[NP][256] @ B^T (B[ncols][256]) ----------------
// 128x128 tile, BK=64, 4 waves (2x2), reg-staged dbuf LDS with XOR-swizzle (T2).

__global__ __launch_bounds__(256, 2) void k_gemm(
    const short* __restrict__ A, const short* __restrict__ B, short* __restrict__ H,
    const int ntiles_n, const int ncols) {
  __shared__ __attribute__((aligned(16))) short As[2][128 * 64];
  __shared__ __attribute__((aligned(16))) short Bs[2][128 * 64];
  const int tid = threadIdx.x;
  const int lane = tid & 63, wv = tid >> 6;
  const int wm = wv >> 1, wn = wv & 1;
  const int llo = lane & 15, lhi = lane >> 4;
  const int mt = blockIdx.x / ntiles_n, nt = blockIdx.x % ntiles_n;
  const int m0 = mt * 128, n0 = nt * 128;

  sh8 ra[4], rb[4];
  auto LD = [&](int ks) {
#pragma unroll
    for (int i = 0; i < 4; i++) {
      int c = i * 256 + tid, row = c >> 3, s = c & 7;
      ra[i] = *(const sh8*)(A + (size_t)(m0 + row) * HID + ks * 64 + s * 8);
      rb[i] = *(const sh8*)(B + (size_t)(n0 + row) * HID + ks * 64 + s * 8);
    }
  };
  auto ST = [&](int buf) {
#pragma unroll
    for (int i = 0; i < 4; i++) {
      int c = i * 256 + tid, row = c >> 3, s = c & 7;
      int sw = s ^ (row & 7);
      *(sh8*)&As[buf][row * 64 + sw * 8] = ra[i];
      *(sh8*)&Bs[buf][row * 64 + sw * 8] = rb[i];
    }
  };

  f4v acc[4][4];
#pragma unroll
  for (int m = 0; m < 4; m++)
#pragma unroll
    for (int n = 0; n < 4; n++) acc[m][n] = (f4v){0.f, 0.f, 0.f, 0.f};

  LD(0); ST(0);
  __syncthreads();
  int cb = 0;
  for (int ks = 0; ks < 4; ks++) {
    if (ks < 3) LD(ks + 1);           // T14-lite: issue next-step loads before compute
#pragma unroll
    for (int kk = 0; kk < 2; kk++) {
      sh8 af[4], bfr[4];
#pragma unroll
      for (int m = 0; m < 4; m++) {
        int row = wm * 64 + m * 16 + llo;
        int kc = kk * 4 + lhi;
        af[m] = *(const sh8*)&As[cb][row * 64 + (kc ^ (row & 7)) * 8];
      }
#pragma unroll
      for (int n = 0; n < 4; n++) {
        int col = wn * 64 + n * 16 + llo;
        int kc = kk * 4 + lhi;
        bfr[n] = *(const sh8*)&Bs[cb][col * 64 + (kc ^ (col & 7)) * 8];
      }
#pragma unroll
      for (int m = 0; m < 4; m++)
#pragma unroll
        for (int n = 0; n < 4; n++)
          acc[m][n] = __builtin_amdgcn_mfma_f32_16x16x32_bf16(af[m], bfr[n], acc[m][n], 0, 0, 0);
    }
    if (ks < 3) ST(cb ^ 1);
    __syncthreads();
    cb ^= 1;
  }
  // C-write: frag mapping col=lane&15, row=4*(lane>>4)+j
#pragma unroll
  for (int m = 0; m < 4; m++)
#pragma unroll
    for (int n = 0; n < 4; n++) {
      int colg = n0 + wn * 64 + n * 16 + llo;
#pragma unroll
      for (int j = 0; j < 4; j++) {
        int rowg = m0 + wm * 64 + m * 16 + lhi * 4 + j;
        H[(size_t)rowg * ncols + colg] = f2bf(acc[m][n][j]);
      }
    }
}

// ---------------- aggregate: one wave per dst row, branchless 4-deep gather ----------------
// flags: 1=first pass (init acc), 2=final pass (apply deginv + self), 4=relu (layer 1)

__global__ __launch_bounds__(256) void k_agg(
    const short* __restrict__ H, const unsigned* __restrict__ offsets,
    const unsigned* __restrict__ payload, const float* __restrict__ deginv,
    float* __restrict__ acc_buf, short* __restrict__ x1b,
    const int cc, const int r0, const int flags) {
  const int lane = threadIdx.x & 63;
  const int wv = threadIdx.x >> 6;
  const int nw = gridDim.x * 4;
  for (int d = blockIdx.x * 4 + wv; d < NP; d += nw) {
    if (d >= N_NODES) {
      if (x1b) *(ushort4*)(x1b + (size_t)d * HID + lane * 4) = make_ushort4(0, 0, 0, 0);
      continue;
    }
    f4v acc;
    if (flags & 1) acc = (f4v){0.f, 0.f, 0.f, 0.f};
    else           acc = *(const f4v*)(acc_buf + (size_t)d * HID + lane * 4);

    unsigned p = offsets[d], e = offsets[d + 1];
    for (; p < e; p += 4) {
#pragma unroll
      for (int u = 0; u < 4; u++) {
        unsigned pp = p + u;
        unsigned pl = payload[(pp < e) ? pp : (e - 1u)];
        int et = (int)(pl >> 16) - r0;
        bool ok = (pp < e) && ((unsigned)et < (unsigned)cc);
        size_t base = ok ? ((size_t)(pl & 0xFFFFu) * cc + et) * HID : 0;
        ushort4 hv = *(const ushort4*)(H + base + lane * 4);
        float w = ok ? 1.f : 0.f;
        acc.x += w * bf2f(hv.x);
        acc.y += w * bf2f(hv.y);
        acc.z += w * bf2f(hv.z);
        acc.w += w * bf2f(hv.w);
      }
    }
    if (flags & 2) {
      float dinv = deginv[d];
      ushort4 sv = *(const ushort4*)(H + ((size_t)d * cc + (cc - 1)) * HID + lane * 4);
      f4v o;
      o.x = acc.x * dinv + bf2f(sv.x);
      o.y = acc.y * dinv + bf2f(sv.y);
      o.z = acc.z * dinv + bf2f(sv.z);
      o.w = acc.w * dinv + bf2f(sv.w);
      if (flags & 4) {
        o.x = fmaxf(o.x, 0.f); o.y = fmaxf(o.y, 0.f);
        o.z = fmaxf(o.z, 0.f); o.w = fmaxf(o.w, 0.f);
      }
      if (x1b) {
        ushort4 s4;
        s4.x = (unsigned short)f2bf(o.x); s4.y = (unsigned short)f2bf(o.y);
        s4.z = (unsigned short)f2bf(o.z); s4.w = (unsigned short)f2bf(o.w);
        *(ushort4*)(x1b + (size_t)d * HID + lane * 4) = s4;
      } else {
        *(f4v*)(acc_buf + (size_t)d * HID + lane * 4) = o;
      }
    } else {
      *(f4v*)(acc_buf + (size_t)d * HID + lane * 4) = acc;
    }
  }
}

// ---------------- launch ----------------

extern "C" void kernel_launch(void* const* d_in, const int* in_sizes, int n_in,
                              void* d_out, int out_size, void* d_ws, size_t ws_size,
                              hipStream_t stream) {
  const int*   eidx   = (const int*)d_in[0];
  const int*   etyp   = (const int*)d_in[1];
  const float* emb    = (const float*)d_in[3];
  const float* bases  = (const float*)d_in[4];
  const float* coeffs = (const float*)d_in[5];
  const float* selfl  = (const float*)d_in[6];
  float* outp = (float*)d_out;
  (void)in_sizes; (void)n_in; (void)out_size;

  char* w = (char*)d_ws;
  size_t off = 0;
  auto alloc = [&](size_t bytes) -> void* {
    void* p = w + off;
    off = (off + bytes + 255) & ~(size_t)255;
    return p;
  };
  unsigned* counts   = (unsigned*)alloc((size_t)N_NODES * 4);     // doubles as cursors
  unsigned* offsets  = (unsigned*)alloc((size_t)(N_NODES + 1) * 4);
  unsigned* partials = (unsigned*)alloc(512 * 4);
  float*    deginv   = (float*)alloc((size_t)N_NODES * 4);
  unsigned* payload  = (unsigned*)alloc((size_t)N_EDGES * 4);
  short*    Wb       = (short*)alloc((size_t)2 * 9 * HID * HID * 2);
  short*    xb       = (short*)alloc((size_t)NP * HID * 2);
  short*    x1b      = xb;  // ALIASED: layer-0 final agg (the only x1b writer) is
                            // stream-ordered after layer-0's last GEMM (the last xb reader)
  const size_t per_rel = (size_t)NP * HID * 2;                    // 25.6 MB
  size_t avail = (ws_size > off) ? (ws_size - off) : 0;
  int crels = (int)(avail / per_rel);
  if (crels > 9) crels = 9;
  if (crels < 1) crels = 1;                                       // min footprint ~57.5 MB
  short* h = (short*)alloc(per_rel * (size_t)crels);

  hipMemsetAsync(counts, 0, (size_t)N_NODES * 4, stream);
  k_count<<<(N_EDGES + 255) / 256, 256, 0, stream>>>(eidx, counts);
  k_deginv<<<(N_NODES + 255) / 256, 256, 0, stream>>>(counts, deginv);
  k_scanA<<<SCAN_NBLK, 256, 0, stream>>>(counts, partials);
  k_scanB<<<1, 512, 0, stream>>>(partials);
  k_scanC<<<SCAN_NBLK, 256, 0, stream>>>(counts, partials, offsets);
  hipMemsetAsync(counts, 0, (size_t)N_NODES * 4, stream);         // reuse as cursors
  k_place<<<(N_EDGES + 255) / 256, 256, 0, stream>>>(eidx, etyp, offsets, counts, payload);
  k_wbuild<<<2 * 9 * HID, 256, 0, stream>>>(bases, coeffs, selfl, Wb);
  k_tobf16<<<(NP * (HID / 8) + 255) / 256, 256, 0, stream>>>(emb, xb);

  for (int l = 0; l < 2; l++) {
    const short* Acur = (l == 0) ? xb : x1b;
    int r0 = 0;
    bool first = true;
    while (r0 < 9) {
      int cc = 9 - r0 < crels ? 9 - r0 : crels;
      bool fin = (r0 + cc == 9);
      k_gemm<<<391 * 2 * cc, 256, 0, stream>>>(
          Acur, Wb + ((size_t)(l * 9 + r0)) * HID * HID, h, 2 * cc, cc * HID);
      int flags = (first ? 1 : 0) | (fin ? 2 : 0) | ((l == 0 && fin) ? 4 : 0);
      k_agg<<<1024, 256, 0, stream>>>(h, offsets, payload, deginv, outp,
                                      (l == 0 && fin) ? x1b : (short*)nullptr,
                                      cc, r0, flags);
      first = false;
      r0 += cc;
    }
  }
}

// Round 9
// 590.563 us; speedup vs baseline: 5.3236x; 1.0868x over previous
//
#include <hip/hip_runtime.h>
#include <hip/hip_bf16.h>

#define N_NODES 50000
#define NP 50048                      // padded rows = 391*128
#define N_EDGES 800000
#define N_REL 8
#define HID 256
#define N_BASES 30
#define SCAN_NBLK ((N_NODES + 1023) / 1024)   // 49

typedef float f4v __attribute__((ext_vector_type(4)));
typedef short sh8 __attribute__((ext_vector_type(8)));
typedef unsigned short u16x8 __attribute__((ext_vector_type(8)));

static __device__ __forceinline__ short f2bf(float f) {
  return __builtin_bit_cast(short, __float2bfloat16(f));
}
static __device__ __forceinline__ float bf2f(unsigned short u) {
  return __builtin_bit_cast(float, ((unsigned)u) << 16);
}
static __device__ __forceinline__ void gload16(const void* g, void* l) {
  __builtin_amdgcn_global_load_lds((const __attribute__((address_space(1))) void*)g,
                                   (__attribute__((address_space(3))) void*)l, 16, 0, 0);
}

// ---------------- preprocessing ----------------

__global__ void k_count(const int* __restrict__ eidx, unsigned* __restrict__ counts) {
  int e = blockIdx.x * 256 + threadIdx.x;
  if (e < N_EDGES) atomicAdd(&counts[eidx[N_EDGES + e]], 1u);
}

__global__ void k_deginv(const unsigned* __restrict__ counts, float* __restrict__ deginv) {
  int d = blockIdx.x * 256 + threadIdx.x;
  if (d < N_NODES) {
    unsigned deg = counts[d];
    deginv[d] = 1.0f / (float)(deg ? deg : 1u);
  }
}

__global__ void k_scanA(const unsigned* __restrict__ counts, unsigned* __restrict__ partials) {
  __shared__ unsigned sm[256];
  int t = threadIdx.x, b = blockIdx.x;
  int g0 = b * 1024 + t * 4;
  unsigned s = 0;
#pragma unroll
  for (int j = 0; j < 4; j++) s += (g0 + j < N_NODES) ? counts[g0 + j] : 0u;
  sm[t] = s;
  __syncthreads();
  for (int st = 128; st > 0; st >>= 1) {
    if (t < st) sm[t] += sm[t + st];
    __syncthreads();
  }
  if (t == 0) partials[b] = sm[0];
}

__global__ void k_scanB(unsigned* __restrict__ partials) {
  __shared__ unsigned sm[512];
  int t = threadIdx.x;
  unsigned v = (t < SCAN_NBLK) ? partials[t] : 0u;
  sm[t] = v;
  __syncthreads();
  for (int s = 1; s < 512; s <<= 1) {
    unsigned add = (t >= s) ? sm[t - s] : 0u;
    __syncthreads();
    sm[t] += add;
    __syncthreads();
  }
  partials[t] = sm[t] - v;  // exclusive
}

__global__ void k_scanC(const unsigned* __restrict__ counts, const unsigned* __restrict__ partials,
                        unsigned* __restrict__ offsets) {
  __shared__ unsigned sm[256];
  int t = threadIdx.x, b = blockIdx.x;
  int g0 = b * 1024 + t * 4;
  unsigned c[4];
#pragma unroll
  for (int j = 0; j < 4; j++) c[j] = (g0 + j < N_NODES) ? counts[g0 + j] : 0u;
  unsigned tsum = c[0] + c[1] + c[2] + c[3];
  sm[t] = tsum;
  __syncthreads();
  for (int s = 1; s < 256; s <<= 1) {
    unsigned add = (t >= s) ? sm[t - s] : 0u;
    __syncthreads();
    sm[t] += add;
    __syncthreads();
  }
  unsigned run = partials[b] + (sm[t] - tsum);
#pragma unroll
  for (int j = 0; j < 4; j++) {
    if (g0 + j < N_NODES) offsets[g0 + j] = run;
    if (g0 + j == N_NODES - 1) offsets[N_NODES] = run + c[j];
    run += c[j];
  }
}

// cursors buffer == counts buffer (re-zeroed after scans consumed counts)
__global__ void k_place(const int* __restrict__ eidx, const int* __restrict__ etyp,
                        const unsigned* __restrict__ offsets, unsigned* __restrict__ cursors,
                        unsigned* __restrict__ payload) {
  int e = blockIdx.x * 256 + threadIdx.x;
  if (e < N_EDGES) {
    int src = eidx[e];
    int dst = eidx[N_EDGES + e];
    int et  = etyp[e];
    unsigned pos = offsets[dst] + atomicAdd(&cursors[dst], 1u);
    payload[pos] = ((unsigned)et << 16) | (unsigned)src;  // et<8, src<65536
  }
}

// W[l][r] = sum_b coeffs[l][r][b]*bases[l][b]; r=8 -> self_loops[l].
// Stored as Wb[l][r][o][k] bf16 (k contiguous) = MFMA B-fragment layout.
__global__ void k_wbuild(const float* __restrict__ bases, const float* __restrict__ coeffs,
                         const float* __restrict__ selfl, short* __restrict__ Wb) {
  int bid = blockIdx.x;
  int k = bid & 255;
  int lr = bid >> 8;  // 0..17
  int r = lr % 9, l = lr / 9;
  int o = threadIdx.x;
  float v;
  if (r == 8) {
    v = selfl[((size_t)l * HID + k) * HID + o];
  } else {
    const float* cf = coeffs + (l * N_REL + r) * N_BASES;
    const float* bp = bases + (((size_t)l * N_BASES) * HID + k) * HID + o;
    float a = 0.f;
#pragma unroll
    for (int b = 0; b < N_BASES; b++) a += cf[b] * bp[(size_t)b * HID * HID];
    v = a;
  }
  Wb[(((size_t)l * 9 + r) * HID + o) * HID + k] = f2bf(v);
}

// f32 -> bf16 convert with zero-padding rows [N_NODES, NP)
__global__ void k_tobf16(const float* __restrict__ src, short* __restrict__ dstp) {
  int i = blockIdx.x * 256 + threadIdx.x;   // index of 8-float group
  if (i >= NP * (HID / 8)) return;
  int row = i >> 5;                          // 32 groups per row
  sh8 v;
  if (row < N_NODES) {
    const float* s = src + (size_t)i * 8;
    f4v a = *(const f4v*)s, b = *(const f4v*)(s + 4);
    v[0] = f2bf(a.x); v[1] = f2bf(a.y); v[2] = f2bf(a.z); v[3] = f2bf(a.w);
    v[4] = f2bf(b.x); v[5] = f2bf(b.y); v[6] = f2bf(b.z); v[7] = f2bf(b.w);
  } else {
    v = (sh8){0, 0, 0, 0, 0, 0, 0, 0};
  }
  *(sh8*)(dstp + (size_t)i * 8) = v;
}

// ---------------- GEMM: H[NP][ncols] = A[NP][256] @ B^T (B[ncols][256]) ----------------
// 128x128 tile, BK=64, 4 waves (2x2). Async global_load_lds staging with
// PRE-SWIZZLED global source (rule #21): LDS slot s of row holds global chunk
// s^(row&7); reads use kc^(row&7) -> conflict-free (2-way only) and zero staging VALU.

__global__ __launch_bounds__(256, 2) void k_gemm(
    const short* __restrict__ A, const short* __restrict__ B, short* __restrict__ H,
    const int ntiles_n, const int ncols) {
  __shared__ __attribute__((aligned(16))) short As[2][128 * 64];
  __shared__ __attribute__((aligned(16))) short Bs[2][128 * 64];
  const int tid = threadIdx.x;
  const int lane = tid & 63, wv = tid >> 6;
  const int wm = wv >> 1, wn = wv & 1;
  const int llo = lane & 15, lhi = lane >> 4;
  const int mt = blockIdx.x / ntiles_n, nt = blockIdx.x % ntiles_n;
  const int m0 = mt * 128, n0 = nt * 128;

  auto STAGE = [&](int buf, int ks) {
#pragma unroll
    for (int i = 0; i < 4; i++) {
      int c = (i * 4 + wv) * 64 + lane;     // chunk id 0..1023 (16B chunks)
      int row = c >> 3, s = c & 7;
      int ss = s ^ (row & 7);               // inverse-swizzled source chunk
      gload16(A + (size_t)(m0 + row) * HID + ks * 64 + ss * 8,
              &As[buf][(i * 4 + wv) * 512]);
      gload16(B + (size_t)(n0 + row) * HID + ks * 64 + ss * 8,
              &Bs[buf][(i * 4 + wv) * 512]);
    }
  };

  f4v acc[4][4];
#pragma unroll
  for (int m = 0; m < 4; m++)
#pragma unroll
    for (int n = 0; n < 4; n++) acc[m][n] = (f4v){0.f, 0.f, 0.f, 0.f};

  STAGE(0, 0);
  __syncthreads();          // compiler inserts vmcnt(0) drain before s_barrier
  int cb = 0;
  for (int ks = 0; ks < 4; ks++) {
    if (ks < 3) STAGE(cb ^ 1, ks + 1);  // async prefetch overlaps this step's MFMAs
#pragma unroll
    for (int kk = 0; kk < 2; kk++) {
      sh8 af[4], bfr[4];
#pragma unroll
      for (int m = 0; m < 4; m++) {
        int row = wm * 64 + m * 16 + llo;
        int kc = kk * 4 + lhi;
        af[m] = *(const sh8*)&As[cb][row * 64 + (kc ^ (row & 7)) * 8];
      }
#pragma unroll
      for (int n = 0; n < 4; n++) {
        int col = wn * 64 + n * 16 + llo;
        int kc = kk * 4 + lhi;
        bfr[n] = *(const sh8*)&Bs[cb][col * 64 + (kc ^ (col & 7)) * 8];
      }
#pragma unroll
      for (int m = 0; m < 4; m++)
#pragma unroll
        for (int n = 0; n < 4; n++)
          acc[m][n] = __builtin_amdgcn_mfma_f32_16x16x32_bf16(af[m], bfr[n], acc[m][n], 0, 0, 0);
    }
    __syncthreads();
    cb ^= 1;
  }
  // C-write: frag mapping col=lane&15, row=4*(lane>>4)+j
#pragma unroll
  for (int m = 0; m < 4; m++)
#pragma unroll
    for (int n = 0; n < 4; n++) {
      int colg = n0 + wn * 64 + n * 16 + llo;
#pragma unroll
      for (int j = 0; j < 4; j++) {
        int rowg = m0 + wm * 64 + m * 16 + lhi * 4 + j;
        H[(size_t)rowg * ncols + colg] = f2bf(acc[m][n][j]);
      }
    }
}

// ---------------- aggregate: one wave per dst row, 2 edges per load instruction ----------------
// Lanes 0-31 serve edge e, lanes 32-63 edge e+1; each lane reads ushort8 (16B) of the
// 512B H row. Halves combined once at flush via shfl_xor(32).
// flags: 1=first pass (init acc), 2=final pass (apply deginv + self), 4=relu (layer 1)

__global__ __launch_bounds__(256) void k_agg(
    const short* __restrict__ H, const unsigned* __restrict__ offsets,
    const unsigned* __restrict__ payload, const float* __restrict__ deginv,
    float* __restrict__ acc_buf, short* __restrict__ x1b,
    const int cc, const int r0, const int flags) {
  const int lane = threadIdx.x & 63;
  const int wv   = threadIdx.x >> 6;
  const int half = lane >> 5;          // edge parity within a pair
  const int col8 = lane & 31;          // 8-element column chunk
  const int col4 = col8 * 8 + half * 4;  // this lane's 4-float flush slot
  const int nw = gridDim.x * 4;
  for (int d = blockIdx.x * 4 + wv; d < NP; d += nw) {
    if (d >= N_NODES) {
      if (x1b) { ushort4 z = make_ushort4(0, 0, 0, 0);
                 *(ushort4*)(x1b + (size_t)d * HID + col4) = z; }
      continue;
    }
    float acc[8];
    if ((flags & 1) || half) {         // only half 0 reloads prior passes (avoid double-count)
#pragma unroll
      for (int j = 0; j < 8; j++) acc[j] = 0.f;
    } else {
      f4v a0 = *(const f4v*)(acc_buf + (size_t)d * HID + col8 * 8);
      f4v a1 = *(const f4v*)(acc_buf + (size_t)d * HID + col8 * 8 + 4);
      acc[0] = a0.x; acc[1] = a0.y; acc[2] = a0.z; acc[3] = a0.w;
      acc[4] = a1.x; acc[5] = a1.y; acc[6] = a1.z; acc[7] = a1.w;
    }

    unsigned p = offsets[d], e = offsets[d + 1];
    for (; p < e; p += 8) {            // 8 edges per iteration (4 pair-loads in flight)
#pragma unroll
      for (int u = 0; u < 4; u++) {
        unsigned ee = p + u * 2 + (unsigned)half;
        unsigned pl = payload[(ee < e) ? ee : (e - 1u)];
        int et = (int)(pl >> 16) - r0;
        bool ok = (ee < e) && ((unsigned)et < (unsigned)cc);
        size_t base = ok ? ((size_t)(pl & 0xFFFFu) * cc + et) * HID : 0;
        u16x8 hv = *(const u16x8*)(H + base + col8 * 8);
        float w = ok ? 1.f : 0.f;
#pragma unroll
        for (int j = 0; j < 8; j++) acc[j] += w * bf2f(hv[j]);
      }
    }
    // combine edge-parity halves
#pragma unroll
    for (int j = 0; j < 8; j++) acc[j] += __shfl_xor(acc[j], 32);

    if (flags & 2) {
      float dinv = deginv[d];
      ushort4 sv = *(const ushort4*)(H + ((size_t)d * cc + (cc - 1)) * HID + col4);
      f4v o;
      o.x = acc[half * 4 + 0] * dinv + bf2f(sv.x);
      o.y = acc[half * 4 + 1] * dinv + bf2f(sv.y);
      o.z = acc[half * 4 + 2] * dinv + bf2f(sv.z);
      o.w = acc[half * 4 + 3] * dinv + bf2f(sv.w);
      if (flags & 4) {
        o.x = fmaxf(o.x, 0.f); o.y = fmaxf(o.y, 0.f);
        o.z = fmaxf(o.z, 0.f); o.w = fmaxf(o.w, 0.f);
      }
      if (x1b) {
        ushort4 s4;
        s4.x = (unsigned short)f2bf(o.x); s4.y = (unsigned short)f2bf(o.y);
        s4.z = (unsigned short)f2bf(o.z); s4.w = (unsigned short)f2bf(o.w);
        *(ushort4*)(x1b + (size_t)d * HID + col4) = s4;
      } else {
        *(f4v*)(acc_buf + (size_t)d * HID + col4) = o;
      }
    } else {
      f4v o;
      o.x = acc[half * 4 + 0]; o.y = acc[half * 4 + 1];
      o.z = acc[half * 4 + 2]; o.w = acc[half * 4 + 3];
      *(f4v*)(acc_buf + (size_t)d * HID + col4) = o;
    }
  }
}

// ---------------- launch ----------------

extern "C" void kernel_launch(void* const* d_in, const int* in_sizes, int n_in,
                              void* d_out, int out_size, void* d_ws, size_t ws_size,
                              hipStream_t stream) {
  const int*   eidx   = (const int*)d_in[0];
  const int*   etyp   = (const int*)d_in[1];
  const float* emb    = (const float*)d_in[3];
  const float* bases  = (const float*)d_in[4];
  const float* coeffs = (const float*)d_in[5];
  const float* selfl  = (const float*)d_in[6];
  float* outp = (float*)d_out;
  (void)in_sizes; (void)n_in; (void)out_size;

  char* w = (char*)d_ws;
  size_t off = 0;
  auto alloc = [&](size_t bytes) -> void* {
    void* p = w + off;
    off = (off + bytes + 255) & ~(size_t)255;
    return p;
  };
  unsigned* counts   = (unsigned*)alloc((size_t)N_NODES * 4);     // doubles as cursors
  unsigned* offsets  = (unsigned*)alloc((size_t)(N_NODES + 1) * 4);
  unsigned* partials = (unsigned*)alloc(512 * 4);
  float*    deginv   = (float*)alloc((size_t)N_NODES * 4);
  unsigned* payload  = (unsigned*)alloc((size_t)N_EDGES * 4);
  short*    Wb       = (short*)alloc((size_t)2 * 9 * HID * HID * 2);
  short*    xb       = (short*)alloc((size_t)NP * HID * 2);
  short*    x1b      = xb;  // ALIASED: layer-0 final agg (the only x1b writer) is
                            // stream-ordered after layer-0's last GEMM (the last xb reader)
  const size_t per_rel = (size_t)NP * HID * 2;                    // 25.6 MB
  size_t avail = (ws_size > off) ? (ws_size - off) : 0;
  int crels = (int)(avail / per_rel);
  if (crels > 9) crels = 9;
  if (crels < 1) crels = 1;                                       // min footprint ~57.5 MB
  short* h = (short*)alloc(per_rel * (size_t)crels);

  hipMemsetAsync(counts, 0, (size_t)N_NODES * 4, stream);
  k_count<<<(N_EDGES + 255) / 256, 256, 0, stream>>>(eidx, counts);
  k_deginv<<<(N_NODES + 255) / 256, 256, 0, stream>>>(counts, deginv);
  k_scanA<<<SCAN_NBLK, 256, 0, stream>>>(counts, partials);
  k_scanB<<<1, 512, 0, stream>>>(partials);
  k_scanC<<<SCAN_NBLK, 256, 0, stream>>>(counts, partials, offsets);
  hipMemsetAsync(counts, 0, (size_t)N_NODES * 4, stream);         // reuse as cursors
  k_place<<<(N_EDGES + 255) / 256, 256, 0, stream>>>(eidx, etyp, offsets, counts, payload);
  k_wbuild<<<2 * 9 * HID, 256, 0, stream>>>(bases, coeffs, selfl, Wb);
  k_tobf16<<<(NP * (HID / 8) + 255) / 256, 256, 0, stream>>>(emb, xb);

  for (int l = 0; l < 2; l++) {
    const short* Acur = (l == 0) ? xb : x1b;
    int r0 = 0;
    bool first = true;
    while (r0 < 9) {
      int cc = 9 - r0 < crels ? 9 - r0 : crels;
      bool fin = (r0 + cc == 9);
      k_gemm<<<391 * 2 * cc, 256, 0, stream>>>(
          Acur, Wb + ((size_t)(l * 9 + r0)) * HID * HID, h, 2 * cc, cc * HID);
      int flags = (first ? 1 : 0) | (fin ? 2 : 0) | ((l == 0 && fin) ? 4 : 0);
      k_agg<<<2048, 256, 0, stream>>>(h, offsets, payload, deginv, outp,
                                      (l == 0 && fin) ? x1b : (short*)nullptr,
                                      cc, r0, flags);
      first = false;
      r0 += cc;
    }
  }
}